// Round 5
// baseline (47954.929 us; speedup 1.0000x reference)
//
#include <hip/hip_runtime.h>
#include <hip/hip_bf16.h>

// ---------------- constants ----------------
static constexpr int kT    = 2048;
static constexpr int kOUT_ELEMS = 2048 * 4096;   // output 0 size

typedef _Float16 half2_t __attribute__((ext_vector_type(2)));

__device__ __forceinline__ unsigned pack_h2(float a, float b) {
  half2_t h{(_Float16)a, (_Float16)b};
  return __builtin_bit_cast(unsigned, h);
}
__device__ __forceinline__ float fdot2u(unsigned a, unsigned b, float c) {
  return __builtin_amdgcn_fdot2(__builtin_bit_cast(half2_t, a),
                                __builtin_bit_cast(half2_t, b), c, false);
}
__device__ __forceinline__ float sigm(float x) {
  return 1.f / (1.f + __expf(-x));
}
__device__ __forceinline__ float tanh_f(float x) {
  float ax = fabsf(x);
  float e = __expf(-2.f * ax);
  float r = (1.f - e) / (1.f + e);
  return x < 0.f ? -r : r;
}

// ---------------- K0: prep (weight concat / bias sums / fp16 Whh pack) ----------------
__global__ __launch_bounds__(256) void prep_kernel(
    const float* __restrict__ enc_Wih, const float* __restrict__ enc_bih,
    const float* __restrict__ cenc_Wih, const float* __restrict__ cenc_bih,
    const float* __restrict__ l0_Whh, const float* __restrict__ l1_Whh,
    const float* __restrict__ l0_bih, const float* __restrict__ l0_bhh,
    const float* __restrict__ l1_bih, const float* __restrict__ l1_bhh,
    float* __restrict__ wcat, float* __restrict__ bcat,
    float* __restrict__ bias0, float* __restrict__ bias1,
    unsigned* __restrict__ wprep) {
  int idx0 = blockIdx.x * blockDim.x + threadIdx.x;
  int stride = gridDim.x * blockDim.x;
  for (int i = idx0; i < 768 * 1024; i += stride) {
    int r = i >> 10, cc = i & 1023;
    wcat[i] = (r < 384) ? enc_Wih[r * 1024 + cc] : cenc_Wih[(r - 384) * 1024 + cc];
  }
  for (int i = idx0; i < 768; i += stride)
    bcat[i] = (i < 384) ? enc_bih[i] : cenc_bih[i - 384];
  for (int i = idx0; i < 2048; i += stride) {
    bias0[i] = l0_bih[i] + l0_bhh[i];
    bias1[i] = l1_bih[i] + l1_bhh[i];
  }
  // wprep [ld][e<128][row<1024] = half2(Whh[ld][row][2e], Whh[ld][row][2e+1])
  for (int i = idx0; i < 2 * 2 * 128 * 1024; i += stride) {
    int row = i & 1023;
    int e = (i >> 10) & 127;
    int ld = i >> 17;  // layer*2 + dir
    const float* W = (ld < 2 ? l0_Whh : l1_Whh) + (ld & 1) * 1024 * 256;
    wprep[i] = pack_h2(W[row * 256 + 2 * e], W[row * 256 + 2 * e + 1]);
  }
}

// ---------------- fp32 tiled GEMM: C[M][N] = A[M][K] * B[N][K]^T + bias[N] ----------------
__global__ __launch_bounds__(256) void gemm_bt(
    const float* __restrict__ A, const float* __restrict__ B,
    const float* __restrict__ bias, float* __restrict__ C,
    int M, int N, int K) {
  __shared__ float As[16][68];
  __shared__ float Bs[16][68];
  int tid = threadIdx.x;
  int tx = tid & 15, ty = tid >> 4;
  int m0 = blockIdx.y * 64, n0 = blockIdx.x * 64;
  int lr = tid >> 2;         // 0..63
  int lc = (tid & 3) << 2;   // 0,4,8,12
  float acc[4][4] = {};
  const float* Ap = A + (long)(m0 + lr) * K + lc;
  const float* Bp = B + (long)(n0 + lr) * K + lc;
  for (int k0 = 0; k0 < K; k0 += 16) {
    float4 a4 = *(const float4*)(Ap + k0);
    float4 b4 = *(const float4*)(Bp + k0);
    __syncthreads();
    As[lc + 0][lr] = a4.x; As[lc + 1][lr] = a4.y; As[lc + 2][lr] = a4.z; As[lc + 3][lr] = a4.w;
    Bs[lc + 0][lr] = b4.x; Bs[lc + 1][lr] = b4.y; Bs[lc + 2][lr] = b4.z; Bs[lc + 3][lr] = b4.w;
    __syncthreads();
#pragma unroll
    for (int kk = 0; kk < 16; kk++) {
      float4 ra = *(const float4*)&As[kk][ty << 2];
      float4 rb = *(const float4*)&Bs[kk][tx << 2];
      float av[4] = {ra.x, ra.y, ra.z, ra.w};
      float bv[4] = {rb.x, rb.y, rb.z, rb.w};
#pragma unroll
      for (int i = 0; i < 4; i++)
#pragma unroll
        for (int jj = 0; jj < 4; jj++)
          acc[i][jj] += av[i] * bv[jj];
    }
  }
#pragma unroll
  for (int i = 0; i < 4; i++) {
    int m = m0 + (ty << 2) + i;
#pragma unroll
    for (int jj = 0; jj < 4; jj++) {
      int n = n0 + (tx << 2) + jj;
      C[(long)m * N + n] = acc[i][jj] + (bias ? bias[n] : 0.f);
    }
  }
}

// ---------------- K3: GRU chains ----------------
__global__ __launch_bounds__(384, 2) void gru_kernel(
    const float* __restrict__ xgg,   // [T][768]  (cols 0..383 enc, 384..767 cenc)
    const float* __restrict__ c_in,  // [T][1024]
    const float* __restrict__ enc_Wih, const float* __restrict__ enc_Whh,
    const float* __restrict__ enc_bih, const float* __restrict__ enc_bhh,
    const float* __restrict__ cenc_Wih, const float* __restrict__ cenc_Whh,
    const float* __restrict__ cenc_bih, const float* __restrict__ cenc_bhh,
    float* __restrict__ u_out, float* __restrict__ cmem_out) {
  int b = blockIdx.x, j = threadIdx.x;
  __shared__ float h_lds[128];
  __shared__ float zb[128], ndot[128], nxg[128];
  if (b < 2) {
    const float* Whh = (b == 0) ? enc_Whh : cenc_Whh;
    const float* bhh = (b == 0) ? enc_bhh : cenc_bhh;
    const float* xp = xgg + b * 384;
    float w[128];
#pragma unroll
    for (int e = 0; e < 128; e++) w[e] = Whh[j * 128 + e];
    float bh = bhh[j];
    if (j < 128) h_lds[j] = 0.f;
    float hreg = 0.f;
    __syncthreads();
    float xgc = xp[j];
    for (int t = 0; t < kT; t++) {
      float xgn = 0.f;
      if (t + 1 < kT) xgn = xp[(t + 1) * 768 + j];
      float dot = bh;
#pragma unroll
      for (int e4 = 0; e4 < 32; e4++) {
        float4 h4 = *(const float4*)&h_lds[e4 * 4];
        dot += w[4 * e4 + 0] * h4.x;
        dot += w[4 * e4 + 1] * h4.y;
        dot += w[4 * e4 + 2] * h4.z;
        dot += w[4 * e4 + 3] * h4.w;
      }
      if (j >= 256) { ndot[j - 256] = dot; nxg[j - 256] = xgc; }
      else if (j >= 128) { zb[j - 128] = xgc + dot; }
      __syncthreads();
      if (j < 128) {
        float r = sigm(xgc + dot);
        float z = sigm(zb[j]);
        float n = tanh_f(nxg[j] + r * ndot[j]);
        hreg = (1.f - z) * n + z * hreg;
        h_lds[j] = hreg;
      }
      __syncthreads();
      xgc = xgn;
    }
    if (j < 128) {
      if (b == 0) u_out[j] = hreg; else cmem_out[j] = hreg;
    }
  } else {
    const float* Wih = ((b == 2) ? enc_Wih : cenc_Wih) + 384 * 1024;
    const float* bih = ((b == 2) ? enc_bih : cenc_bih) + 384;
    const float* bhh = ((b == 2) ? enc_bhh : cenc_bhh) + 384;
    const float* crow = c_in + (long)(kT - 1) * 1024;
    float acc = bih[j];
    for (int k = 0; k < 1024; k += 4) {
      float4 cv = *(const float4*)&crow[k];
      float4 wv = *(const float4*)&Wih[j * 1024 + k];
      acc += cv.x * wv.x + cv.y * wv.y + cv.z * wv.z + cv.w * wv.w;
    }
    float bh = bhh[j];
    if (j >= 256) { ndot[j - 256] = bh; nxg[j - 256] = acc; }
    else if (j >= 128) { zb[j - 128] = acc + bh; }
    __syncthreads();
    if (j < 128) {
      float r = sigm(acc + bh);
      float z = sigm(zb[j]);
      float n = tanh_f(nxg[j] + r * ndot[j]);
      float h = (1.f - z) * n;
      if (b == 2) u_out[128 + j] = h; else cmem_out[128 + j] = h;
    }
  }
}

// ---------------- attention ----------------
__global__ __launch_bounds__(256) void attn_dots(
    const float* __restrict__ mem, const float* __restrict__ u, float* __restrict__ d) {
  __shared__ float us[256];
  int tid = threadIdx.x;
  us[tid] = u[tid];
  __syncthreads();
  int g = tid >> 3, l8 = tid & 7;
  int row = blockIdx.x * 32 + g;
  const float* mr = mem + (long)row * 256 + l8 * 32;
  float p = 0.f;
#pragma unroll
  for (int k = 0; k < 32; k += 4) {
    float4 m4 = *(const float4*)&mr[k];
    p += m4.x * us[l8 * 32 + k] + m4.y * us[l8 * 32 + k + 1] +
         m4.z * us[l8 * 32 + k + 2] + m4.w * us[l8 * 32 + k + 3];
  }
  p += __shfl_down(p, 4);
  p += __shfl_down(p, 2);
  p += __shfl_down(p, 1);
  if (l8 == 0) d[row] = p;
}

__global__ __launch_bounds__(1024) void attn_soft(
    const float* __restrict__ d, float* __restrict__ p, float* __restrict__ h_acc) {
  __shared__ float red[1024];
  int tid = threadIdx.x;
  float v[8];
  float mx = -1e30f;
#pragma unroll
  for (int i = 0; i < 8; i++) { v[i] = d[tid * 8 + i]; mx = fmaxf(mx, v[i]); }
  red[tid] = mx; __syncthreads();
  for (int s = 512; s > 0; s >>= 1) {
    if (tid < s) red[tid] = fmaxf(red[tid], red[tid + s]);
    __syncthreads();
  }
  mx = red[0]; __syncthreads();
  float sm = 0.f; float e[8];
#pragma unroll
  for (int i = 0; i < 8; i++) { e[i] = __expf(v[i] - mx); sm += e[i]; }
  red[tid] = sm; __syncthreads();
  for (int s = 512; s > 0; s >>= 1) {
    if (tid < s) red[tid] += red[tid + s];
    __syncthreads();
  }
  float rz = 1.f / red[0];
#pragma unroll
  for (int i = 0; i < 8; i++) p[tid * 8 + i] = e[i] * rz;
  if (tid < 256) h_acc[tid] = 0.f;   // re-zero every launch (stream-ordered before attn_h)
}

__global__ __launch_bounds__(256) void attn_h(
    const float* __restrict__ mem, const float* __restrict__ p, float* __restrict__ h_acc) {
  int tid = threadIdx.x;
  int r0 = blockIdx.x * 128;
  float acc = 0.f;
  for (int i = 0; i < 128; i++) acc += p[r0 + i] * mem[(long)(r0 + i) * 256 + tid];
  atomicAdd(&h_acc[tid], acc);
}

__global__ __launch_bounds__(128) void attn_o(
    const float* __restrict__ u, const float* __restrict__ h_acc,
    const float* __restrict__ know_W, const float* __restrict__ know_b,
    float* __restrict__ o) {
  __shared__ float uh[256];
  int tid = threadIdx.x;
  uh[tid] = u[tid] + h_acc[tid];
  uh[128 + tid] = u[128 + tid] + h_acc[128 + tid];
  __syncthreads();
  int row = blockIdx.x * 128 + tid;
  float acc = know_b[row];
  for (int k = 0; k < 256; k += 4) {
    float4 w4 = *(const float4*)&know_W[row * 256 + k];
    acc += w4.x * uh[k] + w4.y * uh[k + 1] + w4.z * uh[k + 2] + w4.w * uh[k + 3];
  }
  o[row] = acc;
}

__global__ __launch_bounds__(128) void attn_ov(
    const float* __restrict__ o, const float* __restrict__ Wih0, float* __restrict__ ov) {
  int row = blockIdx.x * 128 + threadIdx.x;
  float acc = 0.f;
  for (int k = 0; k < 1024; k += 4) {
    float4 w4 = *(const float4*)&Wih0[(long)row * 1024 + k];
    float4 o4 = *(const float4*)&o[k];
    acc += w4.x * o4.x + w4.y * o4.y + w4.z * o4.z + w4.w * o4.w;
  }
  ov[row] = acc;
}

// ---------------- LSTM chain v3 (fixed launch bounds) ----------------
// 512 threads (8 waves). __launch_bounds__(512, 1): 1 BLOCK per CU (CUDA-style
// second arg = min blocks/CU on this toolchain; (512,2) compiled to a 128-VGPR
// cap = 4 waves/SIMD and spilled everything). 1 block/CU -> 2 waves/SIMD ->
// 256-VGPR cap; 192 weight regs + ~40 working fits. grid=2 so 2 CUs used.
// Thread j owns rowA=(j>>1)|((j&1)<<8) (even lane: i, odd lane: f)
// and rowB=rowA+512 (even: g, odd: o). 96 half2/row in VGPR, 32 in LDS slab.
// Gate exchange via shfl_xor(1); h pairing via shfl_xor(2); ONE barrier/step.
static constexpr int RP = 96;

__global__ __launch_bounds__(512, 1) void lstm_kernel(
    const unsigned* __restrict__ wprep,  // this layer: [dir][128][1024] half2-packed
    const float* __restrict__ xg,        // [T][2048], col = dir*1024 + row (biases folded)
    const float* __restrict__ extra,     // [2048] rank-1 add or nullptr
    float* __restrict__ out) {           // [T][512], fwd cols 0:256, bwd 256:512
  int dir = blockIdx.x, j = threadIdx.x;          // j in [0,512)
  const int rowA = (j >> 1) | ((j & 1) << 8);     // [0,512)
  const int rowB = rowA + 512;
  __shared__ unsigned wl[1024 * 32];              // 128 KB swizzled weight slab
  __shared__ unsigned h2v[2 * 128];               // packed h double buffer
  const unsigned* wp = wprep + dir * (128 * 1024);

  // LDS weight slab: e in [RP,128) -> 8 uint4 chunks per row, slot = c ^ (row&7)
  for (int i = j; i < 1024 * 32; i += 512) {
    int e = i >> 10;          // 0..31
    int row = i & 1023;
    int c = e >> 2, q = e & 3;
    wl[row * 32 + (((c ^ (row & 7)) << 2) | q)] = wp[(RP + e) * 1024 + row];
  }
  unsigned wA[RP], wB[RP];
#pragma unroll
  for (int e = 0; e < RP; e++) {
    wA[e] = wp[e * 1024 + rowA];
    wB[e] = wp[e * 1024 + rowB];
  }
  float exA = 0.f, exB = 0.f;
  if (extra) { exA = extra[dir * 1024 + rowA]; exB = extra[dir * 1024 + rowB]; }
  if (j < 128) h2v[j] = 0u;
  float cst = 0.f;
  __syncthreads();

  const float* xp = xg + (dir ? 1024 : 0);
  const int t0 = dir ? (kT - 1) : 0;
  const int dt = dir ? -1 : 1;
  const int sl0 = (rowA & 7) << 2;
  const int rAb = rowA * 32, rBb = rowB * 32;
  const bool even = (j & 1) == 0;

  float xA = xp[(long)t0 * 2048 + rowA] + exA;
  float xB = xp[(long)t0 * 2048 + rowB] + exB;

  for (int s = 0; s < kT; ++s) {
    int t = t0 + s * dt;
    float nA = 0.f, nB = 0.f;
    if (s + 1 < kT) {
      const float* xn = xp + (long)(t + dt) * 2048;
      nA = xn[rowA]; nB = xn[rowB];
    }
    const unsigned* hb = &h2v[(s & 1) * 128];
    float accA = xA, accB = xB;

    // register-resident weights: e in [0,RP)
#pragma unroll
    for (int e4 = 0; e4 < RP / 4; ++e4) {
      uint4 hh = *(const uint4*)&hb[e4 * 4];
      accA = fdot2u(wA[4 * e4 + 0], hh.x, accA);
      accA = fdot2u(wA[4 * e4 + 1], hh.y, accA);
      accA = fdot2u(wA[4 * e4 + 2], hh.z, accA);
      accA = fdot2u(wA[4 * e4 + 3], hh.w, accA);
      accB = fdot2u(wB[4 * e4 + 0], hh.x, accB);
      accB = fdot2u(wB[4 * e4 + 1], hh.y, accB);
      accB = fdot2u(wB[4 * e4 + 2], hh.z, accB);
      accB = fdot2u(wB[4 * e4 + 3], hh.w, accB);
    }
    // LDS-resident weights: chunks c in [0,8) -> e = RP + 4c
#pragma unroll
    for (int c = 0; c < 8; ++c) {
      uint4 hh = *(const uint4*)&hb[RP + c * 4];
      int sl = ((c << 2) ^ sl0);
      uint4 qA = *(const uint4*)&wl[rAb + sl];
      uint4 qB = *(const uint4*)&wl[rBb + sl];
      accA = fdot2u(qA.x, hh.x, accA);
      accA = fdot2u(qA.y, hh.y, accA);
      accA = fdot2u(qA.z, hh.z, accA);
      accA = fdot2u(qA.w, hh.w, accA);
      accB = fdot2u(qB.x, hh.x, accB);
      accB = fdot2u(qB.y, hh.y, accB);
      accB = fdot2u(qB.z, hh.z, accB);
      accB = fdot2u(qB.w, hh.w, accB);
    }

    // even lane: accA=i, accB=g ; odd lane: accA=f, accB=o
    float aA = sigm(accA);
    float aB = even ? tanh_f(accB) : sigm(accB);
    float pA = __shfl_xor(aA, 1);
    float pB = __shfl_xor(aB, 1);
    float iv = even ? aA : pA;
    float fv = even ? pA : aA;
    float gv = even ? aB : pB;
    float ov_ = even ? pB : aB;
    cst = fv * cst + iv * gv;            // both lanes of a pair compute identical c_m
    float h = ov_ * tanh_f(cst);
    int m = j >> 1;
    if (even) out[(long)t * 512 + dir * 256 + m] = h;
    float h2 = __shfl_xor(h, 2);
    if ((j & 3) == 0) h2v[((s + 1) & 1) * 128 + (j >> 2)] = pack_h2(h, h2);
    __syncthreads();
    xA = nA + exA; xB = nB + exB;
  }
}

// ---------------- final row softmax ----------------
__global__ __launch_bounds__(256) void softmax_rows(
    const float* __restrict__ logits, float* __restrict__ outp) {
  int t = blockIdx.x, tid = threadIdx.x;
  __shared__ float red[256];
  const float* lr = logits + (long)t * 4096;
  float v[16];
  float mx = -1e30f;
#pragma unroll
  for (int i = 0; i < 16; i++) { v[i] = lr[tid + 256 * i]; mx = fmaxf(mx, v[i]); }
  red[tid] = mx; __syncthreads();
  for (int s = 128; s > 0; s >>= 1) {
    if (tid < s) red[tid] = fmaxf(red[tid], red[tid + s]);
    __syncthreads();
  }
  mx = red[0]; __syncthreads();
  float sm = 0.f;
#pragma unroll
  for (int i = 0; i < 16; i++) { v[i] = __expf(v[i] - mx); sm += v[i]; }
  red[tid] = sm; __syncthreads();
  for (int s = 128; s > 0; s >>= 1) {
    if (tid < s) red[tid] += red[tid + s];
    __syncthreads();
  }
  float rz = 1.f / red[0];
#pragma unroll
  for (int i = 0; i < 16; i++) outp[(long)t * 4096 + tid + 256 * i] = v[i] * rz;
}

// ---------------- launch ----------------
extern "C" void kernel_launch(void* const* d_in, const int* in_sizes, int n_in,
                              void* d_out, int out_size, void* d_ws, size_t ws_size,
                              hipStream_t stream) {
  const float* c        = (const float*)d_in[0];
  const float* memory   = (const float*)d_in[1];
  const float* enc_Wih  = (const float*)d_in[2];
  const float* enc_Whh  = (const float*)d_in[3];
  const float* enc_bih  = (const float*)d_in[4];
  const float* enc_bhh  = (const float*)d_in[5];
  const float* cenc_Wih = (const float*)d_in[6];
  const float* cenc_Whh = (const float*)d_in[7];
  const float* cenc_bih = (const float*)d_in[8];
  const float* cenc_bhh = (const float*)d_in[9];
  const float* know_W   = (const float*)d_in[10];
  const float* know_b   = (const float*)d_in[11];
  const float* l0_Wih   = (const float*)d_in[12];
  const float* l0_Whh   = (const float*)d_in[13];
  const float* l0_bih   = (const float*)d_in[14];
  const float* l0_bhh   = (const float*)d_in[15];
  const float* l1_Wih   = (const float*)d_in[16];
  const float* l1_Whh   = (const float*)d_in[17];
  const float* l1_bih   = (const float*)d_in[18];
  const float* l1_bhh   = (const float*)d_in[19];
  const float* out_W    = (const float*)d_in[20];
  const float* out_b    = (const float*)d_in[21];

  float* ws = (float*)d_ws;
  float* outp = (float*)d_out;

  float* xgg   = ws;                  // 1,572,864   [T][768]
  float* cW    = ws + 1572864;        // 4,194,304   [T][2048]
  float* wcat  = ws + 5767168;        //   786,432
  float* l0out = ws + 6553600;        // 1,048,576   [T][512]
  float* xg1   = ws + 7602176;        // 4,194,304   [T][2048]
  unsigned* wprep = (unsigned*)(ws + 11796480);  // 524,288 u32
  float* bcat  = ws + 12320768;       // 768
  float* bias0 = ws + 12321536;       // 2048
  float* bias1 = ws + 12323584;       // 2048
  float* u_vec = ws + 12325632;       // 256
  float* d_att = ws + 12325888;       // 8192
  float* p_att = ws + 12334080;       // 8192
  float* h_acc = ws + 12342272;       // 256
  float* o_vec = ws + 12342528;       // 1024
  float* ov    = ws + 12343552;       // 2048
  float* l1out = ws + 12345600;       // 1,048,576
  float* logits = ws;                 // 8,388,608   aliases xgg/cW/wcat/l0out/part of xg1

  prep_kernel<<<512, 256, 0, stream>>>(enc_Wih, enc_bih, cenc_Wih, cenc_bih,
                                       l0_Whh, l1_Whh, l0_bih, l0_bhh, l1_bih, l1_bhh,
                                       wcat, bcat, bias0, bias1, wprep);
  gemm_bt<<<dim3(768 / 64, 2048 / 64), 256, 0, stream>>>(c, wcat, bcat, xgg, 2048, 768, 1024);
  gemm_bt<<<dim3(2048 / 64, 2048 / 64), 256, 0, stream>>>(c, l0_Wih, bias0, cW, 2048, 2048, 1024);
  gru_kernel<<<4, 384, 0, stream>>>(xgg, c, enc_Wih, enc_Whh, enc_bih, enc_bhh,
                                    cenc_Wih, cenc_Whh, cenc_bih, cenc_bhh,
                                    u_vec, outp + kOUT_ELEMS);
  attn_dots<<<256, 256, 0, stream>>>(memory, u_vec, d_att);
  attn_soft<<<1, 1024, 0, stream>>>(d_att, p_att, h_acc);
  attn_h<<<64, 256, 0, stream>>>(memory, p_att, h_acc);
  attn_o<<<8, 128, 0, stream>>>(u_vec, h_acc, know_W, know_b, o_vec);
  attn_ov<<<16, 128, 0, stream>>>(o_vec, l0_Wih, ov);
  lstm_kernel<<<2, 512, 0, stream>>>(wprep, cW, ov, l0out);
  gemm_bt<<<dim3(2048 / 64, 2048 / 64), 256, 0, stream>>>(l0out, l1_Wih, bias1, xg1, 2048, 2048, 512);
  lstm_kernel<<<2, 512, 0, stream>>>(wprep + 2 * 131072, xg1, nullptr, l1out);
  gemm_bt<<<dim3(4096 / 64, 2048 / 64), 256, 0, stream>>>(l1out, out_W, out_b, logits, 2048, 4096, 512);
  softmax_rows<<<2048, 256, 0, stream>>>(logits, outp);
}

// Round 6
// 9982.296 us; speedup vs baseline: 4.8040x; 4.8040x over previous
//
#include <hip/hip_runtime.h>
#include <hip/hip_bf16.h>

// ---------------- constants ----------------
static constexpr int kT    = 2048;
static constexpr int kOUT_ELEMS = 2048 * 4096;   // output 0 size

typedef _Float16 half2_t __attribute__((ext_vector_type(2)));

__device__ __forceinline__ unsigned pack_h2(float a, float b) {
  half2_t h{(_Float16)a, (_Float16)b};
  return __builtin_bit_cast(unsigned, h);
}
__device__ __forceinline__ float fdot2u(unsigned a, unsigned b, float c) {
  return __builtin_amdgcn_fdot2(__builtin_bit_cast(half2_t, a),
                                __builtin_bit_cast(half2_t, b), c, false);
}
__device__ __forceinline__ float sigm(float x) {
  return 1.f / (1.f + __expf(-x));
}
__device__ __forceinline__ float tanh_f(float x) {
  float ax = fabsf(x);
  float e = __expf(-2.f * ax);
  float r = (1.f - e) / (1.f + e);
  return x < 0.f ? -r : r;
}

// ---------------- K0: prep (weight concat / bias sums / fp16 Whh pack) ----------------
__global__ __launch_bounds__(256) void prep_kernel(
    const float* __restrict__ enc_Wih, const float* __restrict__ enc_bih,
    const float* __restrict__ cenc_Wih, const float* __restrict__ cenc_bih,
    const float* __restrict__ l0_Whh, const float* __restrict__ l1_Whh,
    const float* __restrict__ l0_bih, const float* __restrict__ l0_bhh,
    const float* __restrict__ l1_bih, const float* __restrict__ l1_bhh,
    float* __restrict__ wcat, float* __restrict__ bcat,
    float* __restrict__ bias0, float* __restrict__ bias1,
    unsigned* __restrict__ wprep) {
  int idx0 = blockIdx.x * blockDim.x + threadIdx.x;
  int stride = gridDim.x * blockDim.x;
  for (int i = idx0; i < 768 * 1024; i += stride) {
    int r = i >> 10, cc = i & 1023;
    wcat[i] = (r < 384) ? enc_Wih[r * 1024 + cc] : cenc_Wih[(r - 384) * 1024 + cc];
  }
  for (int i = idx0; i < 768; i += stride)
    bcat[i] = (i < 384) ? enc_bih[i] : cenc_bih[i - 384];
  for (int i = idx0; i < 2048; i += stride) {
    bias0[i] = l0_bih[i] + l0_bhh[i];
    bias1[i] = l1_bih[i] + l1_bhh[i];
  }
  // wprep [ld][e<128][row<1024] = half2(Whh[ld][row][2e], Whh[ld][row][2e+1])
  for (int i = idx0; i < 2 * 2 * 128 * 1024; i += stride) {
    int row = i & 1023;
    int e = (i >> 10) & 127;
    int ld = i >> 17;  // layer*2 + dir
    const float* W = (ld < 2 ? l0_Whh : l1_Whh) + (ld & 1) * 1024 * 256;
    wprep[i] = pack_h2(W[row * 256 + 2 * e], W[row * 256 + 2 * e + 1]);
  }
}

// ---------------- fp32 tiled GEMM: C[M][N] = A[M][K] * B[N][K]^T + bias[N] ----------------
__global__ __launch_bounds__(256) void gemm_bt(
    const float* __restrict__ A, const float* __restrict__ B,
    const float* __restrict__ bias, float* __restrict__ C,
    int M, int N, int K) {
  __shared__ float As[16][68];
  __shared__ float Bs[16][68];
  int tid = threadIdx.x;
  int tx = tid & 15, ty = tid >> 4;
  int m0 = blockIdx.y * 64, n0 = blockIdx.x * 64;
  int lr = tid >> 2;         // 0..63
  int lc = (tid & 3) << 2;   // 0,4,8,12
  float acc[4][4] = {};
  const float* Ap = A + (long)(m0 + lr) * K + lc;
  const float* Bp = B + (long)(n0 + lr) * K + lc;
  for (int k0 = 0; k0 < K; k0 += 16) {
    float4 a4 = *(const float4*)(Ap + k0);
    float4 b4 = *(const float4*)(Bp + k0);
    __syncthreads();
    As[lc + 0][lr] = a4.x; As[lc + 1][lr] = a4.y; As[lc + 2][lr] = a4.z; As[lc + 3][lr] = a4.w;
    Bs[lc + 0][lr] = b4.x; Bs[lc + 1][lr] = b4.y; Bs[lc + 2][lr] = b4.z; Bs[lc + 3][lr] = b4.w;
    __syncthreads();
#pragma unroll
    for (int kk = 0; kk < 16; kk++) {
      float4 ra = *(const float4*)&As[kk][ty << 2];
      float4 rb = *(const float4*)&Bs[kk][tx << 2];
      float av[4] = {ra.x, ra.y, ra.z, ra.w};
      float bv[4] = {rb.x, rb.y, rb.z, rb.w};
#pragma unroll
      for (int i = 0; i < 4; i++)
#pragma unroll
        for (int jj = 0; jj < 4; jj++)
          acc[i][jj] += av[i] * bv[jj];
    }
  }
#pragma unroll
  for (int i = 0; i < 4; i++) {
    int m = m0 + (ty << 2) + i;
#pragma unroll
    for (int jj = 0; jj < 4; jj++) {
      int n = n0 + (tx << 2) + jj;
      C[(long)m * N + n] = acc[i][jj] + (bias ? bias[n] : 0.f);
    }
  }
}

// ---------------- K3: GRU chains ----------------
__global__ __launch_bounds__(384, 2) void gru_kernel(
    const float* __restrict__ xgg,   // [T][768]  (cols 0..383 enc, 384..767 cenc)
    const float* __restrict__ c_in,  // [T][1024]
    const float* __restrict__ enc_Wih, const float* __restrict__ enc_Whh,
    const float* __restrict__ enc_bih, const float* __restrict__ enc_bhh,
    const float* __restrict__ cenc_Wih, const float* __restrict__ cenc_Whh,
    const float* __restrict__ cenc_bih, const float* __restrict__ cenc_bhh,
    float* __restrict__ u_out, float* __restrict__ cmem_out) {
  int b = blockIdx.x, j = threadIdx.x;
  __shared__ float h_lds[128];
  __shared__ float zb[128], ndot[128], nxg[128];
  if (b < 2) {
    const float* Whh = (b == 0) ? enc_Whh : cenc_Whh;
    const float* bhh = (b == 0) ? enc_bhh : cenc_bhh;
    const float* xp = xgg + b * 384;
    float w[128];
#pragma unroll
    for (int e = 0; e < 128; e++) w[e] = Whh[j * 128 + e];
    float bh = bhh[j];
    if (j < 128) h_lds[j] = 0.f;
    float hreg = 0.f;
    __syncthreads();
    float xgc = xp[j];
    for (int t = 0; t < kT; t++) {
      float xgn = 0.f;
      if (t + 1 < kT) xgn = xp[(t + 1) * 768 + j];
      float dot = bh;
#pragma unroll
      for (int e4 = 0; e4 < 32; e4++) {
        float4 h4 = *(const float4*)&h_lds[e4 * 4];
        dot += w[4 * e4 + 0] * h4.x;
        dot += w[4 * e4 + 1] * h4.y;
        dot += w[4 * e4 + 2] * h4.z;
        dot += w[4 * e4 + 3] * h4.w;
      }
      if (j >= 256) { ndot[j - 256] = dot; nxg[j - 256] = xgc; }
      else if (j >= 128) { zb[j - 128] = xgc + dot; }
      __syncthreads();
      if (j < 128) {
        float r = sigm(xgc + dot);
        float z = sigm(zb[j]);
        float n = tanh_f(nxg[j] + r * ndot[j]);
        hreg = (1.f - z) * n + z * hreg;
        h_lds[j] = hreg;
      }
      __syncthreads();
      xgc = xgn;
    }
    if (j < 128) {
      if (b == 0) u_out[j] = hreg; else cmem_out[j] = hreg;
    }
  } else {
    const float* Wih = ((b == 2) ? enc_Wih : cenc_Wih) + 384 * 1024;
    const float* bih = ((b == 2) ? enc_bih : cenc_bih) + 384;
    const float* bhh = ((b == 2) ? enc_bhh : cenc_bhh) + 384;
    const float* crow = c_in + (long)(kT - 1) * 1024;
    float acc = bih[j];
    for (int k = 0; k < 1024; k += 4) {
      float4 cv = *(const float4*)&crow[k];
      float4 wv = *(const float4*)&Wih[j * 1024 + k];
      acc += cv.x * wv.x + cv.y * wv.y + cv.z * wv.z + cv.w * wv.w;
    }
    float bh = bhh[j];
    if (j >= 256) { ndot[j - 256] = bh; nxg[j - 256] = acc; }
    else if (j >= 128) { zb[j - 128] = acc + bh; }
    __syncthreads();
    if (j < 128) {
      float r = sigm(acc + bh);
      float z = sigm(zb[j]);
      float n = tanh_f(nxg[j] + r * ndot[j]);
      float h = (1.f - z) * n;
      if (b == 2) u_out[128 + j] = h; else cmem_out[128 + j] = h;
    }
  }
}

// ---------------- attention ----------------
__global__ __launch_bounds__(256) void attn_dots(
    const float* __restrict__ mem, const float* __restrict__ u, float* __restrict__ d) {
  __shared__ float us[256];
  int tid = threadIdx.x;
  us[tid] = u[tid];
  __syncthreads();
  int g = tid >> 3, l8 = tid & 7;
  int row = blockIdx.x * 32 + g;
  const float* mr = mem + (long)row * 256 + l8 * 32;
  float p = 0.f;
#pragma unroll
  for (int k = 0; k < 32; k += 4) {
    float4 m4 = *(const float4*)&mr[k];
    p += m4.x * us[l8 * 32 + k] + m4.y * us[l8 * 32 + k + 1] +
         m4.z * us[l8 * 32 + k + 2] + m4.w * us[l8 * 32 + k + 3];
  }
  p += __shfl_down(p, 4);
  p += __shfl_down(p, 2);
  p += __shfl_down(p, 1);
  if (l8 == 0) d[row] = p;
}

__global__ __launch_bounds__(1024) void attn_soft(
    const float* __restrict__ d, float* __restrict__ p, float* __restrict__ h_acc) {
  __shared__ float red[1024];
  int tid = threadIdx.x;
  float v[8];
  float mx = -1e30f;
#pragma unroll
  for (int i = 0; i < 8; i++) { v[i] = d[tid * 8 + i]; mx = fmaxf(mx, v[i]); }
  red[tid] = mx; __syncthreads();
  for (int s = 512; s > 0; s >>= 1) {
    if (tid < s) red[tid] = fmaxf(red[tid], red[tid + s]);
    __syncthreads();
  }
  mx = red[0]; __syncthreads();
  float sm = 0.f; float e[8];
#pragma unroll
  for (int i = 0; i < 8; i++) { e[i] = __expf(v[i] - mx); sm += e[i]; }
  red[tid] = sm; __syncthreads();
  for (int s = 512; s > 0; s >>= 1) {
    if (tid < s) red[tid] += red[tid + s];
    __syncthreads();
  }
  float rz = 1.f / red[0];
#pragma unroll
  for (int i = 0; i < 8; i++) p[tid * 8 + i] = e[i] * rz;
  if (tid < 256) h_acc[tid] = 0.f;   // re-zero every launch (stream-ordered before attn_h)
}

__global__ __launch_bounds__(256) void attn_h(
    const float* __restrict__ mem, const float* __restrict__ p, float* __restrict__ h_acc) {
  int tid = threadIdx.x;
  int r0 = blockIdx.x * 128;
  float acc = 0.f;
  for (int i = 0; i < 128; i++) acc += p[r0 + i] * mem[(long)(r0 + i) * 256 + tid];
  atomicAdd(&h_acc[tid], acc);
}

__global__ __launch_bounds__(128) void attn_o(
    const float* __restrict__ u, const float* __restrict__ h_acc,
    const float* __restrict__ know_W, const float* __restrict__ know_b,
    float* __restrict__ o) {
  __shared__ float uh[256];
  int tid = threadIdx.x;
  uh[tid] = u[tid] + h_acc[tid];
  uh[128 + tid] = u[128 + tid] + h_acc[128 + tid];
  __syncthreads();
  int row = blockIdx.x * 128 + tid;
  float acc = know_b[row];
  for (int k = 0; k < 256; k += 4) {
    float4 w4 = *(const float4*)&know_W[row * 256 + k];
    acc += w4.x * uh[k] + w4.y * uh[k + 1] + w4.z * uh[k + 2] + w4.w * uh[k + 3];
  }
  o[row] = acc;
}

__global__ __launch_bounds__(128) void attn_ov(
    const float* __restrict__ o, const float* __restrict__ Wih0, float* __restrict__ ov) {
  int row = blockIdx.x * 128 + threadIdx.x;
  float acc = 0.f;
  for (int k = 0; k < 1024; k += 4) {
    float4 w4 = *(const float4*)&Wih0[(long)row * 1024 + k];
    float4 o4 = *(const float4*)&o[k];
    acc += w4.x * o4.x + w4.y * o4.y + w4.z * o4.z + w4.w * o4.w;
  }
  ov[row] = acc;
}

// ---------------- LSTM chain v5: 1024 threads, 1 gate-row/thread ----------------
// Per-thread demand DESIGNED under the 128-VGPR tier (which this toolchain pins
// for big blocks): 92 half2 weights in VGPR + 36 half2 in LDS (stride-36 slab,
// non-pow2 stride -> bank-spread, no swizzle needed) = 128 half2/row, all
// on-chip. Thread j owns gate row j (gate = j>>8: 0:i 1:f 2:g 3:o, wave-uniform).
// Gate combine via 4KB gact + 2 barriers/step. 1 WG/CU = 4 waves/EU (natural),
// pinned via amdgpu_waves_per_eu(4,4).
static constexpr int WV = 92;   // e in [0,92)   VGPR   (23 uint4 chunks)
static constexpr int WL = 36;   // e in [92,128) LDS    (9 uint4 chunks)

__global__ __launch_bounds__(1024)
__attribute__((amdgpu_waves_per_eu(4, 4)))
void lstm_kernel(
    const unsigned* __restrict__ wprep,  // this layer: [dir][128][1024] half2-packed
    const float* __restrict__ xg,        // [T][2048], col = dir*1024 + row (biases folded)
    const float* __restrict__ extra,     // [2048] rank-1 add or nullptr
    float* __restrict__ out) {           // [T][512], fwd cols 0:256, bwd 256:512
  const int dir = blockIdx.x, j = threadIdx.x;   // j = gate row, [0,1024)
  __shared__ unsigned wl[1024 * WL];             // 147456 B, [row][36]
  __shared__ float gact[1024];                   // 4 KB
  __shared__ unsigned h2v[128];                  // 512 B packed h
  const unsigned* wp = wprep + dir * (128 * 1024);

  // LDS slab fill: row j's 36 tail-elements (coalesced global reads per e)
  for (int e = 0; e < WL; ++e)
    wl[j * WL + e] = wp[(WV + e) * 1024 + j];
  // VGPR weights: e in [0,92)
  unsigned wv[WV];
#pragma unroll
  for (int e = 0; e < WV; ++e) wv[e] = wp[e * 1024 + j];

  float exv = extra ? extra[dir * 1024 + j] : 0.f;
  if (j < 128) h2v[j] = 0u;
  float cst = 0.f;
  __syncthreads();

  const float* xp = xg + dir * 1024 + j;
  const int t0 = dir ? (kT - 1) : 0;
  const int dt = dir ? -1 : 1;
  const int gate = j >> 8;                       // wave-uniform
  float xc = xp[(long)t0 * 2048] + exv;

  for (int s = 0; s < kT; ++s) {
    const int t = t0 + s * dt;
    float xn = 0.f;
    if (s + 1 < kT) xn = xp[(long)(t + dt) * 2048];
    float acc = xc;
#pragma unroll
    for (int c = 0; c < WV / 4; ++c) {
      uint4 hh = *(const uint4*)&h2v[c * 4];
      acc = fdot2u(wv[4 * c + 0], hh.x, acc);
      acc = fdot2u(wv[4 * c + 1], hh.y, acc);
      acc = fdot2u(wv[4 * c + 2], hh.z, acc);
      acc = fdot2u(wv[4 * c + 3], hh.w, acc);
    }
#pragma unroll
    for (int c = 0; c < WL / 4; ++c) {
      uint4 hh = *(const uint4*)&h2v[WV + c * 4];
      uint4 q  = *(const uint4*)&wl[j * WL + c * 4];
      acc = fdot2u(q.x, hh.x, acc);
      acc = fdot2u(q.y, hh.y, acc);
      acc = fdot2u(q.z, hh.z, acc);
      acc = fdot2u(q.w, hh.w, acc);
    }
    float act = (gate == 2) ? tanh_f(acc) : sigm(acc);
    gact[j] = act;
    __syncthreads();
    if (j < 256) {
      float iv  = gact[j];
      float fv  = gact[256 + j];
      float gv  = gact[512 + j];
      float ov_ = gact[768 + j];
      cst = fv * cst + iv * gv;
      float h = ov_ * tanh_f(cst);
      out[(long)t * 512 + dir * 256 + j] = h;
      float hx = __shfl_xor(h, 1);
      if (!(j & 1)) h2v[j >> 1] = pack_h2(h, hx);
    }
    __syncthreads();
    xc = xn + exv;
  }
}

// ---------------- final row softmax ----------------
__global__ __launch_bounds__(256) void softmax_rows(
    const float* __restrict__ logits, float* __restrict__ outp) {
  int t = blockIdx.x, tid = threadIdx.x;
  __shared__ float red[256];
  const float* lr = logits + (long)t * 4096;
  float v[16];
  float mx = -1e30f;
#pragma unroll
  for (int i = 0; i < 16; i++) { v[i] = lr[tid + 256 * i]; mx = fmaxf(mx, v[i]); }
  red[tid] = mx; __syncthreads();
  for (int s = 128; s > 0; s >>= 1) {
    if (tid < s) red[tid] = fmaxf(red[tid], red[tid + s]);
    __syncthreads();
  }
  mx = red[0]; __syncthreads();
  float sm = 0.f;
#pragma unroll
  for (int i = 0; i < 16; i++) { v[i] = __expf(v[i] - mx); sm += v[i]; }
  red[tid] = sm; __syncthreads();
  for (int s = 128; s > 0; s >>= 1) {
    if (tid < s) red[tid] += red[tid + s];
    __syncthreads();
  }
  float rz = 1.f / red[0];
#pragma unroll
  for (int i = 0; i < 16; i++) outp[(long)t * 4096 + tid + 256 * i] = v[i] * rz;
}

// ---------------- launch ----------------
extern "C" void kernel_launch(void* const* d_in, const int* in_sizes, int n_in,
                              void* d_out, int out_size, void* d_ws, size_t ws_size,
                              hipStream_t stream) {
  const float* c        = (const float*)d_in[0];
  const float* memory   = (const float*)d_in[1];
  const float* enc_Wih  = (const float*)d_in[2];
  const float* enc_Whh  = (const float*)d_in[3];
  const float* enc_bih  = (const float*)d_in[4];
  const float* enc_bhh  = (const float*)d_in[5];
  const float* cenc_Wih = (const float*)d_in[6];
  const float* cenc_Whh = (const float*)d_in[7];
  const float* cenc_bih = (const float*)d_in[8];
  const float* cenc_bhh = (const float*)d_in[9];
  const float* know_W   = (const float*)d_in[10];
  const float* know_b   = (const float*)d_in[11];
  const float* l0_Wih   = (const float*)d_in[12];
  const float* l0_Whh   = (const float*)d_in[13];
  const float* l0_bih   = (const float*)d_in[14];
  const float* l0_bhh   = (const float*)d_in[15];
  const float* l1_Wih   = (const float*)d_in[16];
  const float* l1_Whh   = (const float*)d_in[17];
  const float* l1_bih   = (const float*)d_in[18];
  const float* l1_bhh   = (const float*)d_in[19];
  const float* out_W    = (const float*)d_in[20];
  const float* out_b    = (const float*)d_in[21];

  float* ws = (float*)d_ws;
  float* outp = (float*)d_out;

  float* xgg   = ws;                  // 1,572,864   [T][768]
  float* cW    = ws + 1572864;        // 4,194,304   [T][2048]
  float* wcat  = ws + 5767168;        //   786,432
  float* l0out = ws + 6553600;        // 1,048,576   [T][512]
  float* xg1   = ws + 7602176;        // 4,194,304   [T][2048]
  unsigned* wprep = (unsigned*)(ws + 11796480);  // 524,288 u32
  float* bcat  = ws + 12320768;       // 768
  float* bias0 = ws + 12321536;       // 2048
  float* bias1 = ws + 12323584;       // 2048
  float* u_vec = ws + 12325632;       // 256
  float* d_att = ws + 12325888;       // 8192
  float* p_att = ws + 12334080;       // 8192
  float* h_acc = ws + 12342272;       // 256
  float* o_vec = ws + 12342528;       // 1024
  float* ov    = ws + 12343552;       // 2048
  float* l1out = ws + 12345600;       // 1,048,576
  float* logits = ws;                 // 8,388,608   aliases xgg/cW/wcat/l0out/part of xg1

  prep_kernel<<<512, 256, 0, stream>>>(enc_Wih, enc_bih, cenc_Wih, cenc_bih,
                                       l0_Whh, l1_Whh, l0_bih, l0_bhh, l1_bih, l1_bhh,
                                       wcat, bcat, bias0, bias1, wprep);
  gemm_bt<<<dim3(768 / 64, 2048 / 64), 256, 0, stream>>>(c, wcat, bcat, xgg, 2048, 768, 1024);
  gemm_bt<<<dim3(2048 / 64, 2048 / 64), 256, 0, stream>>>(c, l0_Wih, bias0, cW, 2048, 2048, 1024);
  gru_kernel<<<4, 384, 0, stream>>>(xgg, c, enc_Wih, enc_Whh, enc_bih, enc_bhh,
                                    cenc_Wih, cenc_Whh, cenc_bih, cenc_bhh,
                                    u_vec, outp + kOUT_ELEMS);
  attn_dots<<<256, 256, 0, stream>>>(memory, u_vec, d_att);
  attn_soft<<<1, 1024, 0, stream>>>(d_att, p_att, h_acc);
  attn_h<<<64, 256, 0, stream>>>(memory, p_att, h_acc);
  attn_o<<<8, 128, 0, stream>>>(u_vec, h_acc, know_W, know_b, o_vec);
  attn_ov<<<16, 128, 0, stream>>>(o_vec, l0_Wih, ov);
  lstm_kernel<<<2, 1024, 0, stream>>>(wprep, cW, ov, l0out);
  gemm_bt<<<dim3(2048 / 64, 2048 / 64), 256, 0, stream>>>(l0out, l1_Wih, bias1, xg1, 2048, 2048, 512);
  lstm_kernel<<<2, 1024, 0, stream>>>(wprep + 2 * 131072, xg1, nullptr, l1out);
  gemm_bt<<<dim3(4096 / 64, 2048 / 64), 256, 0, stream>>>(l1out, out_W, out_b, logits, 2048, 4096, 512);
  softmax_rows<<<2048, 256, 0, stream>>>(logits, outp);
}